// Round 9
// baseline (106.547 us; speedup 1.0000x reference)
//
#include <hip/hip_runtime.h>

#define B_ 64
#define Q_ 64
#define L_ 8192
#define KCONV 51
#define HC 26
#define HT 251
#define NCH2 34               // conv501 K-chunks of 16 (shift -6)
#define NCH1 6                // conv51  K-chunks of 16 (shift -7)

// ---- workspace layout (bytes), total 69,345,280 <= proven-safe 73.5 MB ----
// PAR floats: a[0..63] @0, scale @64
#define A51_OFF 512           // 6*64*16 = 6144 B
#define TA_OFF  8192          // 64*34*64*16 = 2,228,224 B
#define RN_OFF  2236416       // rn f16 [B][Q][L] = 67,108,864 B

// exact-balance LDS slot permutation (slot = 16B unit), bijective per 8-slot
// group; applied identically on every write and read.
#define MAPB(s) ((((s) & ~7) | ((((s) & 7) + ((s) >> 3)) & 7)) << 4)

typedef _Float16 f16x8 __attribute__((ext_vector_type(8)));
typedef float f32x16 __attribute__((ext_vector_type(16)));

__device__ __forceinline__ float sigm(float v) {
    return 1.0f / (1.0f + __expf(-v));
}

// ---------------- kernel 1: A-tables (Toeplitz fragments) + a/scale ----------------
__global__ __launch_bounds__(256) void k_params(const float* __restrict__ cwh,
                                                const float* __restrict__ tcw,
                                                const float* __restrict__ araw,
                                                float* __restrict__ ws) {
    const int tid = threadIdx.x;
    const int q = blockIdx.x;
    char* wsb = (char*)ws;
    if (q < Q_) {
        // TA[q][c][lane]: A_c[i=lane&31, kappa=8*(lane>>5)+jj] = kt_q[16c+8hi+jj-i-6]
        for (int idx = tid; idx < NCH2 * 64; idx += 256) {
            int c = idx >> 6, lane = idx & 63;
            int hi = lane >> 5, i = lane & 31;
            int mbase = 16 * c + 8 * hi - i - 6;
            f16x8 hv;
            #pragma unroll
            for (int jj = 0; jj < 8; jj++) {
                int m = mbase + jj;
                float v = 0.0f;
                if (m >= 0 && m <= 500) {
                    int hh = (m <= 250) ? m : (500 - m);
                    v = sigm(tcw[q * HT + hh]);
                }
                hv[jj] = (_Float16)v;
            }
            *(f16x8*)(wsb + TA_OFF + ((size_t)q * (NCH2 * 64) + idx) * 16) = hv;
        }
    } else {
        if (tid < Q_) ws[tid] = sigm(araw[tid]);
        // A51[c][lane]: A_c[i,kappa] = kc[16c+8hi+jj-i-7], kc[m]=cwh[min(m,50-m)]
        for (int idx = tid; idx < NCH1 * 64; idx += 256) {
            int c = idx >> 6, lane = idx & 63;
            int hi = lane >> 5, i = lane & 31;
            int mbase = 16 * c + 8 * hi - i - 7;
            f16x8 hv;
            #pragma unroll
            for (int jj = 0; jj < 8; jj++) {
                int m = mbase + jj;
                float v = 0.0f;
                if (m >= 0 && m < KCONV) v = cwh[m < HC ? m : (KCONV - 1 - m)];
                hv[jj] = (_Float16)v;
            }
            *(f16x8*)(wsb + A51_OFF + idx * 16) = hv;
        }
        __syncthreads();
        if (tid == 0) {
            float p = 1.0f;
            for (int j = 0; j < Q_; j++) p *= ws[j];
            float peak = sigm(tcw[(Q_ - 1) * HT + 250]);
            ws[64] = 1.0f / (peak * p);
        }
    }
}

// ---------------- kernel 2: paired-row all-MFMA conv51 -> softmax -> conv501 ----------
// block = (q, b-pair); 512 threads = 8 waves; wave w owns l-tile [1024w,1024w+1024)
// for BOTH rows. One 17.4 KB buffer per row holds x, then S, then the output.
// 35 KB LDS -> 4 blocks/CU; VGPR capped at 64 for 8 waves/SIMD (32 waves/CU).
__global__ __launch_bounds__(512, 8) void k_fused(const float* __restrict__ x,
                                                  float* __restrict__ ws) {
    const int tid = threadIdx.x;
    const int bid = blockIdx.x;
    const int q = bid >> 5, pr = bid & 31;
    const int row0 = (2 * pr) * Q_ + q, row1 = (2 * pr + 1) * Q_ + q;
    char* wsb = (char*)ws;
    __shared__ __attribute__((aligned(128))) char bufA[17408];  // 1088 slots
    __shared__ __attribute__((aligned(128))) char bufB[17408];
    __shared__ float red[32];

    const int w = tid >> 6, lane = tid & 63, j = lane & 31, hi = lane >> 5;

    // ---- zero halos (slots 0..31 and 1056..1087 of both buffers) ----
    const uint4 z4 = {0u, 0u, 0u, 0u};
    if (tid < 32) {
        *(uint4*)(bufA + MAPB(tid)) = z4;
        *(uint4*)(bufB + MAPB(tid)) = z4;
    } else if (tid >= 64 && tid < 96) {
        int s = 1056 + (tid - 64);
        *(uint4*)(bufA + MAPB(s)) = z4;
        *(uint4*)(bufB + MAPB(s)) = z4;
    }

    // ---- stage both x rows as f16 at halo-256 offset (slots 2t+32, 2t+33) ----
    union H8 { _Float16 h[8]; uint4 u; };
    {
        #pragma unroll
        for (int r = 0; r < 2; r++) {
            const float* xr = x + (size_t)(r ? row1 : row0) * L_ + 16 * tid;
            char* buf = r ? bufB : bufA;
            float4 f0 = *(const float4*)(xr + 0);
            float4 f1 = *(const float4*)(xr + 4);
            float4 f2 = *(const float4*)(xr + 8);
            float4 f3 = *(const float4*)(xr + 12);
            H8 h0, h1;
            h0.h[0] = (_Float16)f0.x; h0.h[1] = (_Float16)f0.y;
            h0.h[2] = (_Float16)f0.z; h0.h[3] = (_Float16)f0.w;
            h0.h[4] = (_Float16)f1.x; h0.h[5] = (_Float16)f1.y;
            h0.h[6] = (_Float16)f1.z; h0.h[7] = (_Float16)f1.w;
            h1.h[0] = (_Float16)f2.x; h1.h[1] = (_Float16)f2.y;
            h1.h[2] = (_Float16)f2.z; h1.h[3] = (_Float16)f2.w;
            h1.h[4] = (_Float16)f3.x; h1.h[5] = (_Float16)f3.y;
            h1.h[6] = (_Float16)f3.z; h1.h[7] = (_Float16)f3.w;
            *(uint4*)(buf + MAPB(2 * tid + 32)) = h0.u;
            *(uint4*)(buf + MAPB(2 * tid + 33)) = h1.u;
        }
    }
    __syncthreads();                                          // S1: x staged

    // ---- conv51 via 6 MFMAs per row (A51 frags L1-hot, shared by all blocks) ----
    f32x16 acc0 = {}, acc1 = {};
    #pragma unroll
    for (int c = 0; c < NCH1; c++) {
        f16x8 a51 = *(const f16x8*)(wsb + A51_OFF + (c * 64 + lane) * 16);
        const int bo = MAPB(128 * w + 4 * j + 2 * c + 28 + hi);
        f16x8 bf0 = *(const f16x8*)(bufA + bo);
        f16x8 bf1 = *(const f16x8*)(bufB + bo);
        acc0 = __builtin_amdgcn_mfma_f32_32x32x16_f16(a51, bf0, acc0, 0, 0, 0);
        acc1 = __builtin_amdgcn_mfma_f32_32x32x16_f16(a51, bf1, acc1, 0, 0, 0);
    }

    // ---- softmax, both rows ----
    float mx0 = -3.402823466e+38f, mx1 = -3.402823466e+38f;
    #pragma unroll
    for (int e = 0; e < 16; e++) { mx0 = fmaxf(mx0, acc0[e]); mx1 = fmaxf(mx1, acc1[e]); }
    #pragma unroll
    for (int o = 32; o > 0; o >>= 1) {
        mx0 = fmaxf(mx0, __shfl_xor(mx0, o));
        mx1 = fmaxf(mx1, __shfl_xor(mx1, o));
    }
    if (lane == 0) { red[w] = mx0; red[8 + w] = mx1; }
    __syncthreads();                                          // S2
    mx0 = red[0]; mx1 = red[8];
    #pragma unroll
    for (int i = 1; i < 8; i++) { mx0 = fmaxf(mx0, red[i]); mx1 = fmaxf(mx1, red[8 + i]); }
    float sm0 = 0.0f, sm1 = 0.0f;
    #pragma unroll
    for (int e = 0; e < 16; e++) {
        acc0[e] = __expf(acc0[e] - mx0); sm0 += acc0[e];
        acc1[e] = __expf(acc1[e] - mx1); sm1 += acc1[e];
    }
    #pragma unroll
    for (int o = 32; o > 0; o >>= 1) { sm0 += __shfl_xor(sm0, o); sm1 += __shfl_xor(sm1, o); }
    if (lane == 0) { red[16 + w] = sm0; red[24 + w] = sm1; }
    __syncthreads();                                          // S3
    float s0 = red[16], s1 = red[24];
    #pragma unroll
    for (int i = 1; i < 8; i++) { s0 += red[16 + i]; s1 += red[24 + i]; }
    const float isum0 = 1.0f / s0, isum1 = 1.0f / s1;

    // ---- write S (f16) via D-layout transpose: e=4k+d -> l = 1024w+32j+8k+4hi+d ----
    union P4 { _Float16 h[4]; uint2 u; };
    #pragma unroll
    for (int k = 0; k < 4; k++) {
        P4 p0, p1;
        #pragma unroll
        for (int d = 0; d < 4; d++) {
            p0.h[d] = (_Float16)(acc0[4 * k + d] * isum0);
            p1.h[d] = (_Float16)(acc1[4 * k + d] * isum1);
        }
        const int bo = MAPB(128 * w + 4 * j + k + 32) + 8 * hi;
        *(uint2*)(bufA + bo) = p0.u;
        *(uint2*)(bufB + bo) = p1.u;
    }
    __syncthreads();                                          // S4: S ready

    // ---- conv501 via 34 chunks; each L2-hot A-frag feeds both rows' MFMAs ----
    const char* tab6 = wsb + TA_OFF + ((size_t)q * (NCH2 * 64) + lane) * 16;
    f32x16 o0 = {}, o1 = {};
    #pragma unroll
    for (int c = 0; c < NCH2; c++) {
        f16x8 af = *(const f16x8*)(tab6 + c * 1024);
        const int bo = MAPB(128 * w + 4 * j + 2 * c + hi);
        f16x8 bf0 = *(const f16x8*)(bufA + bo);
        f16x8 bf1 = *(const f16x8*)(bufB + bo);
        o0 = __builtin_amdgcn_mfma_f32_32x32x16_f16(af, bf0, o0, 0, 0, 0);
        o1 = __builtin_amdgcn_mfma_f32_32x32x16_f16(af, bf1, o1, 0, 0, 0);
    }
    __syncthreads();                                          // S5: S reads done

    // ---- transpose outputs to l-linear (slots 0..1023), coalesced rn store ----
    #pragma unroll
    for (int k = 0; k < 4; k++) {
        P4 p0, p1;
        #pragma unroll
        for (int d = 0; d < 4; d++) {
            p0.h[d] = (_Float16)o0[4 * k + d];
            p1.h[d] = (_Float16)o1[4 * k + d];
        }
        const int bo = MAPB(128 * w + 4 * j + k) + 8 * hi;
        *(uint2*)(bufA + bo) = p0.u;
        *(uint2*)(bufB + bo) = p1.u;
    }
    __syncthreads();                                          // S6
    {
        uint4 r0 = *(uint4*)(bufA + MAPB(2 * tid));
        uint4 r1 = *(uint4*)(bufA + MAPB(2 * tid + 1));
        char* dst = wsb + RN_OFF + ((size_t)row0 * L_ + 16 * tid) * 2;
        *(uint4*)dst = r0;
        *(uint4*)(dst + 16) = r1;
        uint4 r2 = *(uint4*)(bufB + MAPB(2 * tid));
        uint4 r3 = *(uint4*)(bufB + MAPB(2 * tid + 1));
        char* dst1 = wsb + RN_OFF + ((size_t)row1 * L_ + 16 * tid) * 2;
        *(uint4*)dst1 = r2;
        *(uint4*)(dst1 + 16) = r3;
    }
}

// ---------------- kernel 3: serial-q lattice on rn (exact reference scan) ----------------
__global__ __launch_bounds__(256) void k_lat(const float* __restrict__ ws,
                                             float* __restrict__ out) {
    const int tid = threadIdx.x;
    const int T = blockIdx.x & 7, b = blockIdx.x >> 3;
    const char* wsb = (const char*)ws;
    const int l = 1024 * T + 4 * tid;
    const char* src = wsb + RN_OFF + ((size_t)(b * Q_) * L_ + l) * 2;
    float r[4] = {0.0f, 0.0f, 0.0f, 0.0f};
    float t2[4] = {1.0f, 1.0f, 1.0f, 1.0f};
    union P4 { _Float16 h[4]; uint2 u; };
    P4 cur;
    cur.u = *(const uint2*)src;
    for (int q = 0; q < Q_; q++) {
        P4 nxt = cur;
        if (q < Q_ - 1) nxt.u = *(const uint2*)(src + (size_t)(q + 1) * L_ * 2);
        const float aq = ws[q];
        #pragma unroll
        for (int e = 0; e < 4; e++) {
            float rn = (float)cur.h[e], tn = 1.0f - rn;
            float si = 1.0f / (1.0f - aq * r[e] * rn);
            float rnew = r[e] + aq * rn * t2[e] * si;
            t2[e] = aq * t2[e] * tn * tn * si * si;
            r[e] = rnew;
        }
        cur = nxt;
    }
    const float inv_scale = ws[64];
    float4 o;
    o.x = r[0] * inv_scale; o.y = r[1] * inv_scale;
    o.z = r[2] * inv_scale; o.w = r[3] * inv_scale;
    *(float4*)&out[(size_t)b * L_ + l] = o;
}

extern "C" void kernel_launch(void* const* d_in, const int* in_sizes, int n_in,
                              void* d_out, int out_size, void* d_ws, size_t ws_size,
                              hipStream_t stream) {
    (void)in_sizes; (void)n_in; (void)out_size; (void)ws_size;
    const float* x    = (const float*)d_in[0];
    const float* cwh  = (const float*)d_in[1];
    const float* tcw  = (const float*)d_in[2];
    const float* araw = (const float*)d_in[3];
    float* out = (float*)d_out;
    float* ws  = (float*)d_ws;

    hipLaunchKernelGGL(k_params, dim3(Q_ + 1), dim3(256), 0, stream, cwh, tcw, araw, ws);
    hipLaunchKernelGGL(k_fused, dim3((B_ / 2) * Q_), dim3(512), 0, stream, x, ws);
    hipLaunchKernelGGL(k_lat, dim3(B_ * 8), dim3(256), 0, stream, ws, out);
}

// Round 11
// 95.365 us; speedup vs baseline: 1.1173x; 1.1173x over previous
//
#include <hip/hip_runtime.h>

#define B_ 64
#define Q_ 64
#define L_ 8192
#define KCONV 51
#define HC 26
#define HT 251
#define NCH2 34               // conv501 K-chunks of 16 (shift -6)
#define NCH1 6                // conv51  K-chunks of 16 (shift -7)
#define TAL_CH 28             // conv501 chunks staged in LDS (rest from L2)

// ---- workspace layout (bytes), total 69,345,280 <= proven-safe 73.5 MB ----
// PAR floats: a[0..63] @0, scale @64
#define A51_OFF 512           // 6*64*16 = 6144 B
#define TA_OFF  8192          // 64*34*64*16 = 2,228,224 B
#define RN_OFF  2236416       // rn f16 [B][Q][L] = 67,108,864 B

// exact-balance LDS slot permutation (slot = 16B unit), bijective per 8-slot
// group; applied identically on every write and read.
#define MAPB(s) ((((s) & ~7) | ((((s) & 7) + ((s) >> 3)) & 7)) << 4)

typedef _Float16 f16x8 __attribute__((ext_vector_type(8)));
typedef float f32x16 __attribute__((ext_vector_type(16)));
typedef const __attribute__((address_space(1))) void cg_void;
typedef __attribute__((address_space(3))) void lds_void3;

__device__ __forceinline__ float sigm(float v) {
    return 1.0f / (1.0f + __expf(-v));
}

// ---------------- kernel 1: A-tables (Toeplitz fragments) + a/scale ----------------
__global__ __launch_bounds__(256) void k_params(const float* __restrict__ cwh,
                                                const float* __restrict__ tcw,
                                                const float* __restrict__ araw,
                                                float* __restrict__ ws) {
    const int tid = threadIdx.x;
    const int q = blockIdx.x;
    char* wsb = (char*)ws;
    if (q < Q_) {
        // TA[q][c][lane]: A_c[i=lane&31, kappa=8*(lane>>5)+jj] = kt_q[16c+8hi+jj-i-6]
        for (int idx = tid; idx < NCH2 * 64; idx += 256) {
            int c = idx >> 6, lane = idx & 63;
            int hi = lane >> 5, i = lane & 31;
            int mbase = 16 * c + 8 * hi - i - 6;
            f16x8 hv;
            #pragma unroll
            for (int jj = 0; jj < 8; jj++) {
                int m = mbase + jj;
                float v = 0.0f;
                if (m >= 0 && m <= 500) {
                    int hh = (m <= 250) ? m : (500 - m);
                    v = sigm(tcw[q * HT + hh]);
                }
                hv[jj] = (_Float16)v;
            }
            *(f16x8*)(wsb + TA_OFF + ((size_t)q * (NCH2 * 64) + idx) * 16) = hv;
        }
    } else {
        if (tid < Q_) ws[tid] = sigm(araw[tid]);
        // A51[c][lane]: A_c[i,kappa] = kc[16c+8hi+jj-i-7], kc[m]=cwh[min(m,50-m)]
        for (int idx = tid; idx < NCH1 * 64; idx += 256) {
            int c = idx >> 6, lane = idx & 63;
            int hi = lane >> 5, i = lane & 31;
            int mbase = 16 * c + 8 * hi - i - 7;
            f16x8 hv;
            #pragma unroll
            for (int jj = 0; jj < 8; jj++) {
                int m = mbase + jj;
                float v = 0.0f;
                if (m >= 0 && m < KCONV) v = cwh[m < HC ? m : (KCONV - 1 - m)];
                hv[jj] = (_Float16)v;
            }
            *(f16x8*)(wsb + A51_OFF + idx * 16) = hv;
        }
        __syncthreads();
        if (tid == 0) {
            float p = 1.0f;
            for (int j = 0; j < Q_; j++) p *= ws[j];
            float peak = sigm(tcw[(Q_ - 1) * HT + 250]);
            ws[64] = 1.0f / (peak * p);
        }
    }
}

// ---------------- kernel 2: paired-row all-MFMA conv51 -> softmax -> conv501 ----------
// block = (q, b-pair); 512 threads = 8 waves; wave w owns l-tile [1024w,1024w+1024)
// for BOTH rows. TA[q] (28/34 chunks) async-staged to LDS; explicit register
// prefetch rings (af dist 4, bf dist 2) pipeline the MFMA loop; 1-barrier softmax.
__global__ __launch_bounds__(512, 4) void k_fused(const float* __restrict__ x,
                                                  float* __restrict__ ws) {
    const int tid = threadIdx.x;
    const int bid = blockIdx.x;
    const int q = bid >> 5, pr = bid & 31;
    const int row0 = (2 * pr) * Q_ + q, row1 = (2 * pr + 1) * Q_ + q;
    char* wsb = (char*)ws;
    __shared__ __attribute__((aligned(128))) char bufA[17408];  // 1088 slots
    __shared__ __attribute__((aligned(128))) char bufB[17408];
    __shared__ __attribute__((aligned(128))) char TAL[TAL_CH * 1024];
    __shared__ float red[32];

    const int w = tid >> 6, lane = tid & 63, j = lane & 31, hi = lane >> 5;

    // ---- issue async TA[q] -> LDS staging first (overlaps x HBM loads) ----
    {
        const char* tabg = wsb + TA_OFF + (size_t)q * (NCH2 * 64) * 16;
        for (int c = w; c < TAL_CH; c += 8) {
            const void* gp = tabg + (c * 64 + lane) * 16;
            __builtin_amdgcn_global_load_lds((cg_void*)gp,
                                             (lds_void3*)(TAL + c * 1024), 16, 0, 0);
        }
    }

    // ---- preload conv51 A-fragments (latency hidden under x loads) ----
    f16x8 a51r[NCH1];
    #pragma unroll
    for (int c = 0; c < NCH1; c++)
        a51r[c] = *(const f16x8*)(wsb + A51_OFF + (c * 64 + lane) * 16);

    // ---- zero halos (slots 0..31 and 1056..1087 of both buffers) ----
    const uint4 z4 = {0u, 0u, 0u, 0u};
    if (tid < 32) {
        *(uint4*)(bufA + MAPB(tid)) = z4;
        *(uint4*)(bufB + MAPB(tid)) = z4;
    } else if (tid >= 64 && tid < 96) {
        int s = 1056 + (tid - 64);
        *(uint4*)(bufA + MAPB(s)) = z4;
        *(uint4*)(bufB + MAPB(s)) = z4;
    }

    // ---- stage both x rows as f16 at halo-256 offset (slots 2t+32, 2t+33) ----
    union H8 { _Float16 h[8]; uint4 u; };
    {
        #pragma unroll
        for (int r = 0; r < 2; r++) {
            const float* xr = x + (size_t)(r ? row1 : row0) * L_ + 16 * tid;
            char* buf = r ? bufB : bufA;
            float4 f0 = *(const float4*)(xr + 0);
            float4 f1 = *(const float4*)(xr + 4);
            float4 f2 = *(const float4*)(xr + 8);
            float4 f3 = *(const float4*)(xr + 12);
            H8 h0, h1;
            h0.h[0] = (_Float16)f0.x; h0.h[1] = (_Float16)f0.y;
            h0.h[2] = (_Float16)f0.z; h0.h[3] = (_Float16)f0.w;
            h0.h[4] = (_Float16)f1.x; h0.h[5] = (_Float16)f1.y;
            h0.h[6] = (_Float16)f1.z; h0.h[7] = (_Float16)f1.w;
            h1.h[0] = (_Float16)f2.x; h1.h[1] = (_Float16)f2.y;
            h1.h[2] = (_Float16)f2.z; h1.h[3] = (_Float16)f2.w;
            h1.h[4] = (_Float16)f3.x; h1.h[5] = (_Float16)f3.y;
            h1.h[6] = (_Float16)f3.z; h1.h[7] = (_Float16)f3.w;
            *(uint4*)(buf + MAPB(2 * tid + 32)) = h0.u;
            *(uint4*)(buf + MAPB(2 * tid + 33)) = h1.u;
        }
    }
    __syncthreads();                                          // S1: x + TAL ready

    // ---- conv51 via 6 MFMAs per row, bf prefetch ring (dist 2) ----
    f32x16 acc0 = {}, acc1 = {};
    {
        f16x8 pA[2], pB[2];
        pA[0] = *(const f16x8*)(bufA + MAPB(128 * w + 4 * j + 28 + hi));
        pB[0] = *(const f16x8*)(bufB + MAPB(128 * w + 4 * j + 28 + hi));
        pA[1] = *(const f16x8*)(bufA + MAPB(128 * w + 4 * j + 30 + hi));
        pB[1] = *(const f16x8*)(bufB + MAPB(128 * w + 4 * j + 30 + hi));
        #pragma unroll
        for (int c = 0; c < NCH1; c++) {
            acc0 = __builtin_amdgcn_mfma_f32_32x32x16_f16(a51r[c], pA[c & 1], acc0, 0, 0, 0);
            acc1 = __builtin_amdgcn_mfma_f32_32x32x16_f16(a51r[c], pB[c & 1], acc1, 0, 0, 0);
            if (c + 2 < NCH1) {
                const int bo = MAPB(128 * w + 4 * j + 2 * (c + 2) + 28 + hi);
                pA[c & 1] = *(const f16x8*)(bufA + bo);
                pB[c & 1] = *(const f16x8*)(bufB + bo);
            }
        }
    }

    // ---- softmax, both rows, ONE barrier (global fixup folded into isum) ----
    float mx0 = -3.402823466e+38f, mx1 = -3.402823466e+38f;
    #pragma unroll
    for (int e = 0; e < 16; e++) { mx0 = fmaxf(mx0, acc0[e]); mx1 = fmaxf(mx1, acc1[e]); }
    #pragma unroll
    for (int o = 32; o > 0; o >>= 1) {
        mx0 = fmaxf(mx0, __shfl_xor(mx0, o));
        mx1 = fmaxf(mx1, __shfl_xor(mx1, o));
    }
    float sm0 = 0.0f, sm1 = 0.0f;
    #pragma unroll
    for (int e = 0; e < 16; e++) {
        acc0[e] = __expf(acc0[e] - mx0); sm0 += acc0[e];
        acc1[e] = __expf(acc1[e] - mx1); sm1 += acc1[e];
    }
    #pragma unroll
    for (int o = 32; o > 0; o >>= 1) { sm0 += __shfl_xor(sm0, o); sm1 += __shfl_xor(sm1, o); }
    if (lane == 0) {
        red[w] = mx0; red[8 + w] = sm0;
        red[16 + w] = mx1; red[24 + w] = sm1;
    }
    __syncthreads();                                          // S2 (only softmax barrier)
    float mg0 = red[0], mg1 = red[16];
    #pragma unroll
    for (int i = 1; i < 8; i++) { mg0 = fmaxf(mg0, red[i]); mg1 = fmaxf(mg1, red[16 + i]); }
    float ss0 = 0.0f, ss1 = 0.0f;
    #pragma unroll
    for (int i = 0; i < 8; i++) {
        ss0 += red[8 + i] * __expf(red[i] - mg0);
        ss1 += red[24 + i] * __expf(red[16 + i] - mg1);
    }
    const float isum0 = __expf(mx0 - mg0) / ss0;   // per-wave scale, all lanes have mx0
    const float isum1 = __expf(mx1 - mg1) / ss1;

    // ---- write S (f16) via D-layout transpose: e=4k+d -> l = 1024w+32j+8k+4hi+d ----
    union P4 { _Float16 h[4]; uint2 u; };
    #pragma unroll
    for (int k = 0; k < 4; k++) {
        P4 p0, p1;
        #pragma unroll
        for (int d = 0; d < 4; d++) {
            p0.h[d] = (_Float16)(acc0[4 * k + d] * isum0);
            p1.h[d] = (_Float16)(acc1[4 * k + d] * isum1);
        }
        const int bo = MAPB(128 * w + 4 * j + k + 32) + 8 * hi;
        *(uint2*)(bufA + bo) = p0.u;
        *(uint2*)(bufB + bo) = p1.u;
    }
    __syncthreads();                                          // S4: S ready

    // ---- conv501: 34 chunks, explicit pipeline (af ring dist 4, bf ring dist 2) ----
    const char* tab6 = wsb + TA_OFF + ((size_t)q * (NCH2 * 64) + lane) * 16;
    f32x16 o0 = {}, o1 = {};
    {
        f16x8 afr[4], pA[2], pB[2];
        #pragma unroll
        for (int c = 0; c < 4; c++)
            afr[c] = *(const f16x8*)(TAL + c * 1024 + lane * 16);
        #pragma unroll
        for (int c = 0; c < 2; c++) {
            const int bo = MAPB(128 * w + 4 * j + 2 * c + hi);
            pA[c] = *(const f16x8*)(bufA + bo);
            pB[c] = *(const f16x8*)(bufB + bo);
        }
        #pragma unroll
        for (int c = 0; c < NCH2; c++) {
            o0 = __builtin_amdgcn_mfma_f32_32x32x16_f16(afr[c & 3], pA[c & 1], o0, 0, 0, 0);
            o1 = __builtin_amdgcn_mfma_f32_32x32x16_f16(afr[c & 3], pB[c & 1], o1, 0, 0, 0);
            if (c + 2 < NCH2) {
                const int bo = MAPB(128 * w + 4 * j + 2 * (c + 2) + hi);
                pA[c & 1] = *(const f16x8*)(bufA + bo);
                pB[c & 1] = *(const f16x8*)(bufB + bo);
            }
            if (c + 4 < NCH2) {
                afr[c & 3] = (c + 4 < TAL_CH)
                    ? *(const f16x8*)(TAL + (c + 4) * 1024 + lane * 16)
                    : *(const f16x8*)(tab6 + (c + 4) * 1024);
            }
        }
    }
    __syncthreads();                                          // S5: S reads done

    // ---- transpose outputs to l-linear (slots 0..1023), coalesced rn store ----
    #pragma unroll
    for (int k = 0; k < 4; k++) {
        P4 p0, p1;
        #pragma unroll
        for (int d = 0; d < 4; d++) {
            p0.h[d] = (_Float16)o0[4 * k + d];
            p1.h[d] = (_Float16)o1[4 * k + d];
        }
        const int bo = MAPB(128 * w + 4 * j + k) + 8 * hi;
        *(uint2*)(bufA + bo) = p0.u;
        *(uint2*)(bufB + bo) = p1.u;
    }
    __syncthreads();                                          // S6
    {
        uint4 r0 = *(uint4*)(bufA + MAPB(2 * tid));
        uint4 r1 = *(uint4*)(bufA + MAPB(2 * tid + 1));
        char* dst = wsb + RN_OFF + ((size_t)row0 * L_ + 16 * tid) * 2;
        *(uint4*)dst = r0;
        *(uint4*)(dst + 16) = r1;
        uint4 r2 = *(uint4*)(bufB + MAPB(2 * tid));
        uint4 r3 = *(uint4*)(bufB + MAPB(2 * tid + 1));
        char* dst1 = wsb + RN_OFF + ((size_t)row1 * L_ + 16 * tid) * 2;
        *(uint4*)dst1 = r2;
        *(uint4*)(dst1 + 16) = r3;
    }
}

// ---------------- kernel 3: serial-q lattice on rn (exact reference scan) ----------------
__global__ __launch_bounds__(256) void k_lat(const float* __restrict__ ws,
                                             float* __restrict__ out) {
    const int tid = threadIdx.x;
    const int T = blockIdx.x & 7, b = blockIdx.x >> 3;
    const char* wsb = (const char*)ws;
    const int l = 1024 * T + 4 * tid;
    const char* src = wsb + RN_OFF + ((size_t)(b * Q_) * L_ + l) * 2;
    float r[4] = {0.0f, 0.0f, 0.0f, 0.0f};
    float t2[4] = {1.0f, 1.0f, 1.0f, 1.0f};
    union P4 { _Float16 h[4]; uint2 u; };
    P4 cur;
    cur.u = *(const uint2*)src;
    for (int q = 0; q < Q_; q++) {
        P4 nxt = cur;
        if (q < Q_ - 1) nxt.u = *(const uint2*)(src + (size_t)(q + 1) * L_ * 2);
        const float aq = ws[q];
        #pragma unroll
        for (int e = 0; e < 4; e++) {
            float rn = (float)cur.h[e], tn = 1.0f - rn;
            float si = 1.0f / (1.0f - aq * r[e] * rn);
            float rnew = r[e] + aq * rn * t2[e] * si;
            t2[e] = aq * t2[e] * tn * tn * si * si;
            r[e] = rnew;
        }
        cur = nxt;
    }
    const float inv_scale = ws[64];
    float4 o;
    o.x = r[0] * inv_scale; o.y = r[1] * inv_scale;
    o.z = r[2] * inv_scale; o.w = r[3] * inv_scale;
    *(float4*)&out[(size_t)b * L_ + l] = o;
}

extern "C" void kernel_launch(void* const* d_in, const int* in_sizes, int n_in,
                              void* d_out, int out_size, void* d_ws, size_t ws_size,
                              hipStream_t stream) {
    (void)in_sizes; (void)n_in; (void)out_size; (void)ws_size;
    const float* x    = (const float*)d_in[0];
    const float* cwh  = (const float*)d_in[1];
    const float* tcw  = (const float*)d_in[2];
    const float* araw = (const float*)d_in[3];
    float* out = (float*)d_out;
    float* ws  = (float*)d_ws;

    hipLaunchKernelGGL(k_params, dim3(Q_ + 1), dim3(256), 0, stream, cwh, tcw, araw, ws);
    hipLaunchKernelGGL(k_fused, dim3((B_ / 2) * Q_), dim3(512), 0, stream, x, ws);
    hipLaunchKernelGGL(k_lat, dim3(B_ * 8), dim3(256), 0, stream, ws, out);
}